// Round 1
// baseline (1093.672 us; speedup 1.0000x reference)
//
#include <hip/hip_runtime.h>
#include <math.h>

#define N_NODES 100000
#define N_EDGES 1600000
#define F_IN 256
#define HEADS 4
#define HIDDEN 64
#define NEG_SLOPE 0.2f

// ---- monotone float<->uint encoding for atomicMax on floats ----
__device__ __forceinline__ unsigned enc_f(float f) {
    unsigned b = __float_as_uint(f);
    return (b & 0x80000000u) ? ~b : (b | 0x80000000u);
}
__device__ __forceinline__ float dec_f(unsigned e) {
    unsigned b = (e & 0x80000000u) ? (e & 0x7FFFFFFFu) : ~e;
    return __uint_as_float(b);
}

// ---- K0: fold att_src/att_dst/fc_w through lin_w ----
// w_all rows: [0..3]=w_src[h], [4..7]=w_dst[h], [8..11]=w_g[h]; each row 256 floats.
// c0 = dot(bias, fc_w) + fc_b
__global__ __launch_bounds__(256) void prep_kernel(
        const float* __restrict__ lin_w, const float* __restrict__ att_src,
        const float* __restrict__ att_dst, const float* __restrict__ fc_w,
        const float* __restrict__ bias, const float* __restrict__ fc_b,
        float* __restrict__ w_all, float* __restrict__ c0) {
    __shared__ float red[256];
    int h = blockIdx.x;   // 0..3
    int f = threadIdx.x;  // 0..255
    float a0 = 0.f, a1 = 0.f, a2 = 0.f;
    for (int c = 0; c < HIDDEN; ++c) {
        float lw = lin_w[(size_t)(h * HIDDEN + c) * F_IN + f];
        a0 += att_src[h * HIDDEN + c] * lw;
        a1 += att_dst[h * HIDDEN + c] * lw;
        a2 += fc_w[h * HIDDEN + c] * lw;
    }
    w_all[(0 + h) * F_IN + f] = a0;
    w_all[(4 + h) * F_IN + f] = a1;
    w_all[(8 + h) * F_IN + f] = a2;
    if (h == 0) {
        red[f] = bias[f] * fc_w[f];
        __syncthreads();
        for (int s = 128; s; s >>= 1) {
            if (f < s) red[f] += red[f + s];
            __syncthreads();
        }
        if (f == 0) c0[0] = red[0] + fc_b[0];
    }
}

// ---- K1: per-node 256x12 matvec -> srcfeat[n][8]={a_src[4],g[4]}, dstfeat[n][4]={a_dst} ----
// One 16-lane group per node (4 nodes per wave).
__global__ __launch_bounds__(256) void node_kernel(
        const float* __restrict__ x, const float* __restrict__ w_all,
        float* __restrict__ srcfeat, float* __restrict__ dstfeat) {
    int tid  = blockIdx.x * 256 + threadIdx.x;
    int wave = tid >> 6;
    int lane = threadIdx.x & 63;
    int sub  = lane >> 4;
    int l16  = lane & 15;
    int n = wave * 4 + sub;
    if (n >= N_NODES) return;
    const float4* xr = (const float4*)x + (size_t)n * 64;  // 64 float4 per row
    const float4* wr = (const float4*)w_all;
    float p[12];
#pragma unroll
    for (int r = 0; r < 12; ++r) p[r] = 0.f;
#pragma unroll
    for (int k = 0; k < 4; ++k) {
        float4 xv = xr[l16 + 16 * k];
#pragma unroll
        for (int r = 0; r < 12; ++r) {
            float4 wv = wr[r * 64 + l16 + 16 * k];
            p[r] += xv.x * wv.x + xv.y * wv.y + xv.z * wv.z + xv.w * wv.w;
        }
    }
#pragma unroll
    for (int r = 0; r < 12; ++r) {
        float v = p[r];
        v += __shfl_xor(v, 1);
        v += __shfl_xor(v, 2);
        v += __shfl_xor(v, 4);
        v += __shfl_xor(v, 8);
        p[r] = v;
    }
    if (l16 == 0) {
        float* sf = srcfeat + (size_t)n * 8;
        sf[0] = p[0];  sf[1] = p[1];  sf[2] = p[2];  sf[3] = p[3];
        sf[4] = p[8];  sf[5] = p[9];  sf[6] = p[10]; sf[7] = p[11];
        float* df = dstfeat + (size_t)n * 4;
        df[0] = p[4];  df[1] = p[5];  df[2] = p[6];  df[3] = p[7];
    }
}

// ---- K2: init accumulators ----
__global__ __launch_bounds__(256) void init_kernel(
        unsigned* __restrict__ menc, float* __restrict__ num, float* __restrict__ den) {
    int i = blockIdx.x * 256 + threadIdx.x;
    if (i < N_NODES * HEADS) {
        menc[i] = enc_f(-3.0e38f);
        num[i]  = 0.f;
        den[i]  = 0.f;
    }
}

// ---- K3: segment-max of leaky_relu scores over dst ----
__global__ __launch_bounds__(256) void edge_max_kernel(
        const int* __restrict__ ei, const float* __restrict__ srcfeat,
        const float* __restrict__ dstfeat, unsigned* __restrict__ menc) {
    int e = blockIdx.x * 256 + threadIdx.x;
    if (e >= N_EDGES) return;
    int s = ei[e];
    int d = ei[N_EDGES + e];
    float4 as = *(const float4*)(srcfeat + (size_t)s * 8);
    float4 ad = *(const float4*)(dstfeat + (size_t)d * 4);
    float sc[4] = {as.x + ad.x, as.y + ad.y, as.z + ad.z, as.w + ad.w};
    unsigned* mp = menc + (size_t)d * 4;
#pragma unroll
    for (int h = 0; h < 4; ++h) {
        float v = sc[h] > 0.f ? sc[h] : NEG_SLOPE * sc[h];
        atomicMax(mp + h, enc_f(v));
    }
}

// ---- K4: accumulate num += ex*g[src], den += ex ----
__global__ __launch_bounds__(256) void edge_acc_kernel(
        const int* __restrict__ ei, const float* __restrict__ srcfeat,
        const float* __restrict__ dstfeat, const unsigned* __restrict__ menc,
        float* __restrict__ num, float* __restrict__ den) {
    int e = blockIdx.x * 256 + threadIdx.x;
    if (e >= N_EDGES) return;
    int s = ei[e];
    int d = ei[N_EDGES + e];
    const float4* sp = (const float4*)(srcfeat + (size_t)s * 8);
    float4 as = sp[0];
    float4 g  = sp[1];
    float4 ad = *(const float4*)(dstfeat + (size_t)d * 4);
    uint4 me = *(const uint4*)(menc + (size_t)d * 4);
    float sc[4] = {as.x + ad.x, as.y + ad.y, as.z + ad.z, as.w + ad.w};
    float m[4] = {dec_f(me.x), dec_f(me.y), dec_f(me.z), dec_f(me.w)};
    float gg[4] = {g.x, g.y, g.z, g.w};
    float* np = num + (size_t)d * 4;
    float* dp = den + (size_t)d * 4;
#pragma unroll
    for (int h = 0; h < 4; ++h) {
        float v = sc[h] > 0.f ? sc[h] : NEG_SLOPE * sc[h];
        float ex = __expf(v - m[h]);
        atomicAdd(dp + h, ex);
        atomicAdd(np + h, ex * gg[h]);
    }
}

// ---- K5: y[n] = c0 + sum_h num/(den+1e-16) ----
__global__ __launch_bounds__(256) void finalize_kernel(
        const float* __restrict__ num, const float* __restrict__ den,
        const float* __restrict__ c0, float* __restrict__ out) {
    int n = blockIdx.x * 256 + threadIdx.x;
    if (n >= N_NODES) return;
    float4 nu = *(const float4*)(num + (size_t)n * 4);
    float4 de = *(const float4*)(den + (size_t)n * 4);
    float y = c0[0]
            + nu.x / (de.x + 1e-16f)
            + nu.y / (de.y + 1e-16f)
            + nu.z / (de.z + 1e-16f)
            + nu.w / (de.w + 1e-16f);
    out[n] = y;
}

extern "C" void kernel_launch(void* const* d_in, const int* in_sizes, int n_in,
                              void* d_out, int out_size, void* d_ws, size_t ws_size,
                              hipStream_t stream) {
    const float* x       = (const float*)d_in[0];
    const int*   ei      = (const int*)d_in[1];
    const float* lin_w   = (const float*)d_in[2];
    const float* att_src = (const float*)d_in[3];
    const float* att_dst = (const float*)d_in[4];
    const float* bias    = (const float*)d_in[5];
    const float* fc_w    = (const float*)d_in[6];
    const float* fc_b    = (const float*)d_in[7];
    float* out = (float*)d_out;

    float* ws = (float*)d_ws;
    float*    w_all   = ws;                       // 3072 floats
    float*    c0      = ws + 3072;                // 1
    float*    srcfeat = ws + 4096;                // 800000
    float*    dstfeat = ws + 804096;              // 400000
    unsigned* menc    = (unsigned*)(ws + 1204096);// 400000
    float*    num     = ws + 1604096;             // 400000
    float*    den     = ws + 2004096;             // 400000  (total ~9.62 MB)

    prep_kernel<<<4, 256, 0, stream>>>(lin_w, att_src, att_dst, fc_w, bias, fc_b, w_all, c0);
    init_kernel<<<(N_NODES * HEADS + 255) / 256, 256, 0, stream>>>(menc, num, den);
    node_kernel<<<(N_NODES / 4 * 64) / 256, 256, 0, stream>>>(x, w_all, srcfeat, dstfeat);
    edge_max_kernel<<<N_EDGES / 256, 256, 0, stream>>>(ei, srcfeat, dstfeat, menc);
    edge_acc_kernel<<<N_EDGES / 256, 256, 0, stream>>>(ei, srcfeat, dstfeat, menc, num, den);
    finalize_kernel<<<(N_NODES + 255) / 256, 256, 0, stream>>>(num, den, c0, out);
}

// Round 2
// 403.480 us; speedup vs baseline: 2.7106x; 2.7106x over previous
//
#include <hip/hip_runtime.h>
#include <math.h>

#define N_NODES 100000
#define N_EDGES 1600000
#define F_IN 256
#define HIDDEN 64
#define NEG_SLOPE 0.2f
#define NB_SCAN 391  // ceil(100000/256)

// ---- K0: fold att_src/att_dst/fc_w through lin_w ----
// w_all rows: [0..3]=w_src[h], [4..7]=w_dst[h], [8..11]=w_g[h]; each row 256 floats.
// c0 = dot(bias, fc_w) + fc_b
__global__ __launch_bounds__(256) void prep_kernel(
        const float* __restrict__ lin_w, const float* __restrict__ att_src,
        const float* __restrict__ att_dst, const float* __restrict__ fc_w,
        const float* __restrict__ bias, const float* __restrict__ fc_b,
        float* __restrict__ w_all, float* __restrict__ c0) {
    __shared__ float red[256];
    int h = blockIdx.x;   // 0..3
    int f = threadIdx.x;  // 0..255
    float a0 = 0.f, a1 = 0.f, a2 = 0.f;
    for (int c = 0; c < HIDDEN; ++c) {
        float lw = lin_w[(size_t)(h * HIDDEN + c) * F_IN + f];
        a0 += att_src[h * HIDDEN + c] * lw;
        a1 += att_dst[h * HIDDEN + c] * lw;
        a2 += fc_w[h * HIDDEN + c] * lw;
    }
    w_all[(0 + h) * F_IN + f] = a0;
    w_all[(4 + h) * F_IN + f] = a1;
    w_all[(8 + h) * F_IN + f] = a2;
    if (h == 0) {
        red[f] = bias[f] * fc_w[f];
        __syncthreads();
        for (int s = 128; s; s >>= 1) {
            if (f < s) red[f] += red[f + s];
            __syncthreads();
        }
        if (f == 0) c0[0] = red[0] + fc_b[0];
    }
}

// ---- K1: per-node 256x12 matvec -> srcfeat[n][8]={a_src[4],g[4]}, dstfeat[n][4]={a_dst} ----
__global__ __launch_bounds__(256) void node_kernel(
        const float* __restrict__ x, const float* __restrict__ w_all,
        float* __restrict__ srcfeat, float* __restrict__ dstfeat) {
    int tid  = blockIdx.x * 256 + threadIdx.x;
    int wave = tid >> 6;
    int lane = threadIdx.x & 63;
    int sub  = lane >> 4;
    int l16  = lane & 15;
    int n = wave * 4 + sub;
    if (n >= N_NODES) return;
    const float4* xr = (const float4*)x + (size_t)n * 64;
    const float4* wr = (const float4*)w_all;
    float p[12];
#pragma unroll
    for (int r = 0; r < 12; ++r) p[r] = 0.f;
#pragma unroll
    for (int k = 0; k < 4; ++k) {
        float4 xv = xr[l16 + 16 * k];
#pragma unroll
        for (int r = 0; r < 12; ++r) {
            float4 wv = wr[r * 64 + l16 + 16 * k];
            p[r] += xv.x * wv.x + xv.y * wv.y + xv.z * wv.z + xv.w * wv.w;
        }
    }
#pragma unroll
    for (int r = 0; r < 12; ++r) {
        float v = p[r];
        v += __shfl_xor(v, 1);
        v += __shfl_xor(v, 2);
        v += __shfl_xor(v, 4);
        v += __shfl_xor(v, 8);
        p[r] = v;
    }
    if (l16 == 0) {
        float* sf = srcfeat + (size_t)n * 8;
        sf[0] = p[0];  sf[1] = p[1];  sf[2] = p[2];  sf[3] = p[3];
        sf[4] = p[8];  sf[5] = p[9];  sf[6] = p[10]; sf[7] = p[11];
        float* df = dstfeat + (size_t)n * 4;
        df[0] = p[4];  df[1] = p[5];  df[2] = p[6];  df[3] = p[7];
    }
}

// =================== CSR-sort path ===================

__global__ __launch_bounds__(256) void zero_deg_kernel(int* __restrict__ deg) {
    int i = blockIdx.x * 256 + threadIdx.x;
    if (i < N_NODES) deg[i] = 0;
}

__global__ __launch_bounds__(256) void hist_kernel(
        const int* __restrict__ ei, int* __restrict__ deg) {
    int e = blockIdx.x * 256 + threadIdx.x;
    if (e >= N_EDGES) return;
    atomicAdd(deg + ei[N_EDGES + e], 1);
}

__global__ __launch_bounds__(256) void scan1_kernel(
        const int* __restrict__ deg, int* __restrict__ blocksum) {
    __shared__ int red[256];
    int t = threadIdx.x, b = blockIdx.x;
    int d = b * 256 + t;
    red[t] = (d < N_NODES) ? deg[d] : 0;
    __syncthreads();
    for (int s = 128; s; s >>= 1) {
        if (t < s) red[t] += red[t + s];
        __syncthreads();
    }
    if (t == 0) blocksum[b] = red[0];
}

__global__ __launch_bounds__(512) void scan2_kernel(int* __restrict__ blocksum) {
    __shared__ int sc[512];
    int t = threadIdx.x;
    int v = (t < NB_SCAN) ? blocksum[t] : 0;
    sc[t] = v;
    __syncthreads();
    for (int off = 1; off < 512; off <<= 1) {
        int tmp = (t >= off) ? sc[t - off] : 0;
        __syncthreads();
        sc[t] += tmp;
        __syncthreads();
    }
    if (t < NB_SCAN) blocksum[t] = sc[t] - v;  // exclusive
}

__global__ __launch_bounds__(256) void scan3_kernel(
        const int* __restrict__ deg, const int* __restrict__ blocksum,
        int* __restrict__ cursor) {
    __shared__ int sc[256];
    int t = threadIdx.x, b = blockIdx.x;
    int d = b * 256 + t;
    int v = (d < N_NODES) ? deg[d] : 0;
    sc[t] = v;
    __syncthreads();
    for (int off = 1; off < 256; off <<= 1) {
        int tmp = (t >= off) ? sc[t - off] : 0;
        __syncthreads();
        sc[t] += tmp;
        __syncthreads();
    }
    if (d < N_NODES) cursor[d] = blocksum[b] + sc[t] - v;  // exclusive start
}

__global__ __launch_bounds__(256) void scatter_kernel(
        const int* __restrict__ ei, int* __restrict__ cursor,
        int* __restrict__ sorted_src) {
    int e = blockIdx.x * 256 + threadIdx.x;
    if (e >= N_EDGES) return;
    int s = ei[e];
    int d = ei[N_EDGES + e];
    int pos = atomicAdd(cursor + d, 1);
    sorted_src[pos] = s;
}

// After scatter, cursor[n] == end of segment n == start of segment n+1.
// One 16-lane group per node; no max subtraction (exp(e) safe: |e| <~ 8).
__global__ __launch_bounds__(256) void agg_kernel(
        const int* __restrict__ sorted_src, const int* __restrict__ cursor,
        const float* __restrict__ srcfeat, const float* __restrict__ dstfeat,
        const float* __restrict__ c0, float* __restrict__ out) {
    int tid = blockIdx.x * 256 + threadIdx.x;
    int n = tid >> 4;
    int l = tid & 15;
    if (n >= N_NODES) return;
    int begin = (n == 0) ? 0 : cursor[n - 1];
    int end = cursor[n];
    float4 ad = *(const float4*)(dstfeat + (size_t)n * 4);
    float nu[4] = {0.f, 0.f, 0.f, 0.f};
    float de[4] = {0.f, 0.f, 0.f, 0.f};
    for (int i = begin + l; i < end; i += 16) {
        int s = sorted_src[i];
        const float4* sp = (const float4*)(srcfeat + (size_t)s * 8);
        float4 as = sp[0];
        float4 g  = sp[1];
        float sc[4] = {as.x + ad.x, as.y + ad.y, as.z + ad.z, as.w + ad.w};
        float gg[4] = {g.x, g.y, g.z, g.w};
#pragma unroll
        for (int h = 0; h < 4; ++h) {
            float v = sc[h] > 0.f ? sc[h] : NEG_SLOPE * sc[h];
            float ex = __expf(v);
            de[h] += ex;
            nu[h] += ex * gg[h];
        }
    }
#pragma unroll
    for (int h = 0; h < 4; ++h) {
#pragma unroll
        for (int m = 1; m < 16; m <<= 1) {
            nu[h] += __shfl_xor(nu[h], m);
            de[h] += __shfl_xor(de[h], m);
        }
    }
    if (l == 0) {
        float y = c0[0];
#pragma unroll
        for (int h = 0; h < 4; ++h) y += nu[h] / (de[h] + 1e-16f);
        out[n] = y;
    }
}

// =================== fallback atomic path (small ws) ===================

__global__ __launch_bounds__(256) void init_nd_kernel(
        float* __restrict__ num, float* __restrict__ den) {
    int i = blockIdx.x * 256 + threadIdx.x;
    if (i < N_NODES * 4) { num[i] = 0.f; den[i] = 0.f; }
}

__global__ __launch_bounds__(256) void edge_acc2_kernel(
        const int* __restrict__ ei, const float* __restrict__ srcfeat,
        const float* __restrict__ dstfeat, float* __restrict__ num,
        float* __restrict__ den) {
    int e = blockIdx.x * 256 + threadIdx.x;
    if (e >= N_EDGES) return;
    int s = ei[e];
    int d = ei[N_EDGES + e];
    const float4* sp = (const float4*)(srcfeat + (size_t)s * 8);
    float4 as = sp[0];
    float4 g  = sp[1];
    float4 ad = *(const float4*)(dstfeat + (size_t)d * 4);
    float sc[4] = {as.x + ad.x, as.y + ad.y, as.z + ad.z, as.w + ad.w};
    float gg[4] = {g.x, g.y, g.z, g.w};
    float* np = num + (size_t)d * 4;
    float* dp = den + (size_t)d * 4;
#pragma unroll
    for (int h = 0; h < 4; ++h) {
        float v = sc[h] > 0.f ? sc[h] : NEG_SLOPE * sc[h];
        float ex = __expf(v);
        atomicAdd(dp + h, ex);
        atomicAdd(np + h, ex * gg[h]);
    }
}

__global__ __launch_bounds__(256) void finalize_kernel(
        const float* __restrict__ num, const float* __restrict__ den,
        const float* __restrict__ c0, float* __restrict__ out) {
    int n = blockIdx.x * 256 + threadIdx.x;
    if (n >= N_NODES) return;
    float4 nu = *(const float4*)(num + (size_t)n * 4);
    float4 de = *(const float4*)(den + (size_t)n * 4);
    out[n] = c0[0]
           + nu.x / (de.x + 1e-16f)
           + nu.y / (de.y + 1e-16f)
           + nu.z / (de.z + 1e-16f)
           + nu.w / (de.w + 1e-16f);
}

extern "C" void kernel_launch(void* const* d_in, const int* in_sizes, int n_in,
                              void* d_out, int out_size, void* d_ws, size_t ws_size,
                              hipStream_t stream) {
    const float* x       = (const float*)d_in[0];
    const int*   ei      = (const int*)d_in[1];
    const float* lin_w   = (const float*)d_in[2];
    const float* att_src = (const float*)d_in[3];
    const float* att_dst = (const float*)d_in[4];
    const float* bias    = (const float*)d_in[5];
    const float* fc_w    = (const float*)d_in[6];
    const float* fc_b    = (const float*)d_in[7];
    float* out = (float*)d_out;

    float* ws = (float*)d_ws;
    float* w_all   = ws;            // 3072
    float* c0      = ws + 3072;     // 1
    float* srcfeat = ws + 4096;     // 800000
    float* dstfeat = ws + 804096;   // 400000

    prep_kernel<<<4, 256, 0, stream>>>(lin_w, att_src, att_dst, fc_w, bias, fc_b, w_all, c0);
    node_kernel<<<(N_NODES + 15) / 16, 256, 0, stream>>>(x, w_all, srcfeat, dstfeat);

    if (ws_size >= 12018688) {
        // CSR-sort path
        int* deg        = (int*)(ws + 1204096);  // 100000
        int* cursor     = (int*)(ws + 1304096);  // 100000
        int* blocksum   = (int*)(ws + 1404096);  // 512
        int* sorted_src = (int*)(ws + 1404608);  // 1600000

        zero_deg_kernel<<<NB_SCAN, 256, 0, stream>>>(deg);
        hist_kernel<<<N_EDGES / 256, 256, 0, stream>>>(ei, deg);
        scan1_kernel<<<NB_SCAN, 256, 0, stream>>>(deg, blocksum);
        scan2_kernel<<<1, 512, 0, stream>>>(blocksum);
        scan3_kernel<<<NB_SCAN, 256, 0, stream>>>(deg, blocksum, cursor);
        scatter_kernel<<<N_EDGES / 256, 256, 0, stream>>>(ei, cursor, sorted_src);
        agg_kernel<<<(N_NODES * 16) / 256, 256, 0, stream>>>(
            sorted_src, cursor, srcfeat, dstfeat, c0, out);
    } else {
        // fallback: direct atomic accumulation (no max pass)
        float* num = ws + 1204096;  // 400000
        float* den = ws + 1604096;  // 400000
        init_nd_kernel<<<(N_NODES * 4 + 255) / 256, 256, 0, stream>>>(num, den);
        edge_acc2_kernel<<<N_EDGES / 256, 256, 0, stream>>>(ei, srcfeat, dstfeat, num, den);
        finalize_kernel<<<(N_NODES + 255) / 256, 256, 0, stream>>>(num, den, c0, out);
    }
}

// Round 3
// 339.241 us; speedup vs baseline: 3.2239x; 1.1894x over previous
//
#include <hip/hip_runtime.h>
#include <math.h>

#define N_NODES 100000
#define N_EDGES 1600000
#define F_IN 256
#define HIDDEN 64
#define NEG_SLOPE 0.2f

#define W_BUCKETS 391          // ceil(N_NODES/256), bucket = dst>>8
#define B_SC 384               // histogram/scatter blocks
#define CHUNK 4167             // ceil(N_EDGES/B_SC)
#define M_OFF (W_BUCKETS * B_SC)  // 150144
#define NB1 587                // ceil(M_OFF/256)

// ---- K0: fold att_src/att_dst/fc_w through lin_w ----
__global__ __launch_bounds__(256) void prep_kernel(
        const float* __restrict__ lin_w, const float* __restrict__ att_src,
        const float* __restrict__ att_dst, const float* __restrict__ fc_w,
        const float* __restrict__ bias, const float* __restrict__ fc_b,
        float* __restrict__ w_all, float* __restrict__ c0) {
    __shared__ float red[256];
    int h = blockIdx.x;   // 0..3
    int f = threadIdx.x;  // 0..255
    float a0 = 0.f, a1 = 0.f, a2 = 0.f;
    for (int c = 0; c < HIDDEN; ++c) {
        float lw = lin_w[(size_t)(h * HIDDEN + c) * F_IN + f];
        a0 += att_src[h * HIDDEN + c] * lw;
        a1 += att_dst[h * HIDDEN + c] * lw;
        a2 += fc_w[h * HIDDEN + c] * lw;
    }
    w_all[(0 + h) * F_IN + f] = a0;
    w_all[(4 + h) * F_IN + f] = a1;
    w_all[(8 + h) * F_IN + f] = a2;
    if (h == 0) {
        red[f] = bias[f] * fc_w[f];
        __syncthreads();
        for (int s = 128; s; s >>= 1) {
            if (f < s) red[f] += red[f + s];
            __syncthreads();
        }
        if (f == 0) c0[0] = red[0] + fc_b[0];
    }
}

// ---- K1: per-node 256x12 matvec ----
__global__ __launch_bounds__(256) void node_kernel(
        const float* __restrict__ x, const float* __restrict__ w_all,
        float* __restrict__ srcfeat, float* __restrict__ dstfeat) {
    int tid  = blockIdx.x * 256 + threadIdx.x;
    int wave = tid >> 6;
    int lane = threadIdx.x & 63;
    int sub  = lane >> 4;
    int l16  = lane & 15;
    int n = wave * 4 + sub;
    if (n >= N_NODES) return;
    const float4* xr = (const float4*)x + (size_t)n * 64;
    const float4* wr = (const float4*)w_all;
    float p[12];
#pragma unroll
    for (int r = 0; r < 12; ++r) p[r] = 0.f;
#pragma unroll
    for (int k = 0; k < 4; ++k) {
        float4 xv = xr[l16 + 16 * k];
#pragma unroll
        for (int r = 0; r < 12; ++r) {
            float4 wv = wr[r * 64 + l16 + 16 * k];
            p[r] += xv.x * wv.x + xv.y * wv.y + xv.z * wv.z + xv.w * wv.w;
        }
    }
#pragma unroll
    for (int r = 0; r < 12; ++r) {
        float v = p[r];
        v += __shfl_xor(v, 1);
        v += __shfl_xor(v, 2);
        v += __shfl_xor(v, 4);
        v += __shfl_xor(v, 8);
        p[r] = v;
    }
    if (l16 == 0) {
        float* sf = srcfeat + (size_t)n * 8;
        sf[0] = p[0];  sf[1] = p[1];  sf[2] = p[2];  sf[3] = p[3];
        sf[4] = p[8];  sf[5] = p[9];  sf[6] = p[10]; sf[7] = p[11];
        float* df = dstfeat + (size_t)n * 4;
        df[0] = p[4];  df[1] = p[5];  df[2] = p[6];  df[3] = p[7];
    }
}

// =================== LDS-privatized counting sort ===================

// hist[k*B_SC + b] = #edges of block b with dst>>8 == k   (no global atomics)
__global__ __launch_bounds__(256) void hist2_kernel(
        const int* __restrict__ ei, int* __restrict__ hist) {
    __shared__ int lcnt[W_BUCKETS];
    int t = threadIdx.x, b = blockIdx.x;
    for (int i = t; i < W_BUCKETS; i += 256) lcnt[i] = 0;
    __syncthreads();
    int base = b * CHUNK;
    int end = base + CHUNK; if (end > N_EDGES) end = N_EDGES;
    for (int e = base + t; e < end; e += 256)
        atomicAdd(&lcnt[ei[N_EDGES + e] >> 8], 1);
    __syncthreads();
    for (int i = t; i < W_BUCKETS; i += 256) hist[i * B_SC + b] = lcnt[i];
}

__global__ __launch_bounds__(256) void scan1_kernel(
        const int* __restrict__ hist, int* __restrict__ bsum) {
    __shared__ int red[256];
    int t = threadIdx.x, b = blockIdx.x;
    int i = b * 256 + t;
    red[t] = (i < M_OFF) ? hist[i] : 0;
    __syncthreads();
    for (int s = 128; s; s >>= 1) {
        if (t < s) red[t] += red[t + s];
        __syncthreads();
    }
    if (t == 0) bsum[b] = red[0];
}

__global__ __launch_bounds__(1024) void scan2_kernel(int* __restrict__ bsum) {
    __shared__ int sc[1024];
    int t = threadIdx.x;
    int v = (t < NB1) ? bsum[t] : 0;
    sc[t] = v;
    __syncthreads();
    for (int off = 1; off < 1024; off <<= 1) {
        int tmp = (t >= off) ? sc[t - off] : 0;
        __syncthreads();
        sc[t] += tmp;
        __syncthreads();
    }
    if (t < NB1) bsum[t] = sc[t] - v;  // exclusive
}

// in-place exclusive scan of hist -> global offsets
__global__ __launch_bounds__(256) void scan3_kernel(
        int* __restrict__ hist, const int* __restrict__ bsum) {
    __shared__ int sc[256];
    int t = threadIdx.x, b = blockIdx.x;
    int i = b * 256 + t;
    int v = (i < M_OFF) ? hist[i] : 0;
    sc[t] = v;
    __syncthreads();
    for (int off = 1; off < 256; off <<= 1) {
        int tmp = (t >= off) ? sc[t - off] : 0;
        __syncthreads();
        sc[t] += tmp;
        __syncthreads();
    }
    if (i < M_OFF) hist[i] = bsum[b] + sc[t] - v;
}

// place edges: sorted[pos] = src | (dst&255)<<17 ; offsets consumed from LDS
__global__ __launch_bounds__(256) void scatter2_kernel(
        const int* __restrict__ ei, const int* __restrict__ goff,
        int* __restrict__ sorted) {
    __shared__ int lbase[W_BUCKETS];
    int t = threadIdx.x, b = blockIdx.x;
    for (int i = t; i < W_BUCKETS; i += 256) lbase[i] = goff[i * B_SC + b];
    __syncthreads();
    int base = b * CHUNK;
    int end = base + CHUNK; if (end > N_EDGES) end = N_EDGES;
    for (int e = base + t; e < end; e += 256) {
        int s = ei[e];
        int d = ei[N_EDGES + e];
        int pos = atomicAdd(&lbase[d >> 8], 1);
        sorted[pos] = s | ((d & 255) << 17);
    }
}

// one block per bucket: LDS accumulators, fused finalize
__global__ __launch_bounds__(256) void agg2_kernel(
        const int* __restrict__ sorted, const int* __restrict__ goff,
        const float* __restrict__ srcfeat, const float* __restrict__ dstfeat,
        const float* __restrict__ c0, float* __restrict__ out) {
    __shared__ float acc[8][256];  // [0..3]=den[h], [4..7]=num[h]; bank = off%32
    __shared__ float4 lad[256];
    int t = threadIdx.x, k = blockIdx.x;
#pragma unroll
    for (int i = 0; i < 8; ++i) acc[i][t] = 0.f;
    int n0 = k * 256 + t;
    if (n0 < N_NODES) lad[t] = *(const float4*)(dstfeat + (size_t)n0 * 4);
    else lad[t] = make_float4(0.f, 0.f, 0.f, 0.f);
    __syncthreads();
    int begin = goff[k * B_SC];
    int end = (k == W_BUCKETS - 1) ? N_EDGES : goff[(k + 1) * B_SC];
    for (int i = begin + t; i < end; i += 256) {
        int p = sorted[i];
        int s = p & 0x1FFFF;
        int off = p >> 17;
        const float4* sp = (const float4*)(srcfeat + (size_t)s * 8);
        float4 as = sp[0];
        float4 g  = sp[1];
        float4 ad = lad[off];
        float s0 = as.x + ad.x, s1 = as.y + ad.y, s2 = as.z + ad.z, s3 = as.w + ad.w;
        float e0 = __expf(s0 > 0.f ? s0 : NEG_SLOPE * s0);
        float e1 = __expf(s1 > 0.f ? s1 : NEG_SLOPE * s1);
        float e2 = __expf(s2 > 0.f ? s2 : NEG_SLOPE * s2);
        float e3 = __expf(s3 > 0.f ? s3 : NEG_SLOPE * s3);
        atomicAdd(&acc[0][off], e0);
        atomicAdd(&acc[1][off], e1);
        atomicAdd(&acc[2][off], e2);
        atomicAdd(&acc[3][off], e3);
        atomicAdd(&acc[4][off], e0 * g.x);
        atomicAdd(&acc[5][off], e1 * g.y);
        atomicAdd(&acc[6][off], e2 * g.z);
        atomicAdd(&acc[7][off], e3 * g.w);
    }
    __syncthreads();
    if (n0 < N_NODES) {
        float y = c0[0];
        y += acc[4][t] / (acc[0][t] + 1e-16f);
        y += acc[5][t] / (acc[1][t] + 1e-16f);
        y += acc[6][t] / (acc[2][t] + 1e-16f);
        y += acc[7][t] / (acc[3][t] + 1e-16f);
        out[n0] = y;
    }
}

// =================== fallback atomic path (small ws) ===================

__global__ __launch_bounds__(256) void init_nd_kernel(
        float* __restrict__ num, float* __restrict__ den) {
    int i = blockIdx.x * 256 + threadIdx.x;
    if (i < N_NODES * 4) { num[i] = 0.f; den[i] = 0.f; }
}

__global__ __launch_bounds__(256) void edge_acc2_kernel(
        const int* __restrict__ ei, const float* __restrict__ srcfeat,
        const float* __restrict__ dstfeat, float* __restrict__ num,
        float* __restrict__ den) {
    int e = blockIdx.x * 256 + threadIdx.x;
    if (e >= N_EDGES) return;
    int s = ei[e];
    int d = ei[N_EDGES + e];
    const float4* sp = (const float4*)(srcfeat + (size_t)s * 8);
    float4 as = sp[0];
    float4 g  = sp[1];
    float4 ad = *(const float4*)(dstfeat + (size_t)d * 4);
    float sc[4] = {as.x + ad.x, as.y + ad.y, as.z + ad.z, as.w + ad.w};
    float gg[4] = {g.x, g.y, g.z, g.w};
    float* np = num + (size_t)d * 4;
    float* dp = den + (size_t)d * 4;
#pragma unroll
    for (int h = 0; h < 4; ++h) {
        float v = sc[h] > 0.f ? sc[h] : NEG_SLOPE * sc[h];
        float ex = __expf(v);
        atomicAdd(dp + h, ex);
        atomicAdd(np + h, ex * gg[h]);
    }
}

__global__ __launch_bounds__(256) void finalize_kernel(
        const float* __restrict__ num, const float* __restrict__ den,
        const float* __restrict__ c0, float* __restrict__ out) {
    int n = blockIdx.x * 256 + threadIdx.x;
    if (n >= N_NODES) return;
    float4 nu = *(const float4*)(num + (size_t)n * 4);
    float4 de = *(const float4*)(den + (size_t)n * 4);
    out[n] = c0[0]
           + nu.x / (de.x + 1e-16f)
           + nu.y / (de.y + 1e-16f)
           + nu.z / (de.z + 1e-16f)
           + nu.w / (de.w + 1e-16f);
}

extern "C" void kernel_launch(void* const* d_in, const int* in_sizes, int n_in,
                              void* d_out, int out_size, void* d_ws, size_t ws_size,
                              hipStream_t stream) {
    const float* x       = (const float*)d_in[0];
    const int*   ei      = (const int*)d_in[1];
    const float* lin_w   = (const float*)d_in[2];
    const float* att_src = (const float*)d_in[3];
    const float* att_dst = (const float*)d_in[4];
    const float* bias    = (const float*)d_in[5];
    const float* fc_w    = (const float*)d_in[6];
    const float* fc_b    = (const float*)d_in[7];
    float* out = (float*)d_out;

    float* ws = (float*)d_ws;
    float* w_all   = ws;            // 3072
    float* c0      = ws + 3072;     // 1 (pad to 4096)
    float* srcfeat = ws + 4096;     // 800000
    float* dstfeat = ws + 804096;   // 400000

    prep_kernel<<<4, 256, 0, stream>>>(lin_w, att_src, att_dst, fc_w, bias, fc_b, w_all, c0);
    node_kernel<<<(N_NODES + 15) / 16, 256, 0, stream>>>(x, w_all, srcfeat, dstfeat);

    if (ws_size >= (size_t)2955264 * 4) {
        int* hist   = (int*)(ws + 1204096);  // M_OFF = 150144 (becomes offsets)
        int* bsum   = (int*)(ws + 1354240);  // 1024
        int* sorted = (int*)(ws + 1355264);  // 1600000  -> total 2955264 words

        hist2_kernel<<<B_SC, 256, 0, stream>>>(ei, hist);
        scan1_kernel<<<NB1, 256, 0, stream>>>(hist, bsum);
        scan2_kernel<<<1, 1024, 0, stream>>>(bsum);
        scan3_kernel<<<NB1, 256, 0, stream>>>(hist, bsum);
        scatter2_kernel<<<B_SC, 256, 0, stream>>>(ei, hist, sorted);
        agg2_kernel<<<W_BUCKETS, 256, 0, stream>>>(sorted, hist, srcfeat, dstfeat, c0, out);
    } else {
        float* num = ws + 1204096;  // 400000
        float* den = ws + 1604096;  // 400000
        init_nd_kernel<<<(N_NODES * 4 + 255) / 256, 256, 0, stream>>>(num, den);
        edge_acc2_kernel<<<N_EDGES / 256, 256, 0, stream>>>(ei, srcfeat, dstfeat, num, den);
        finalize_kernel<<<(N_NODES + 255) / 256, 256, 0, stream>>>(num, den, c0, out);
    }
}

// Round 4
// 328.339 us; speedup vs baseline: 3.3309x; 1.0332x over previous
//
#include <hip/hip_runtime.h>
#include <math.h>

#define N_NODES 100000
#define N_EDGES 1600000
#define F_IN 256
#define HIDDEN 64
#define NEG_SLOPE 0.2f

#define W_BUCKETS 391          // ceil(N_NODES/256), bucket = dst>>8
#define B_SC 384               // histogram/scatter blocks
#define CHUNK 4167             // ceil(N_EDGES/B_SC)
#define M_OFF (W_BUCKETS * B_SC)  // 150144
#define NB1 587                // ceil(M_OFF/256)
#define MAX_SPLIT 8

// ---- K0: fold att_src/att_dst/fc_w through lin_w ----
__global__ __launch_bounds__(256) void prep_kernel(
        const float* __restrict__ lin_w, const float* __restrict__ att_src,
        const float* __restrict__ att_dst, const float* __restrict__ fc_w,
        const float* __restrict__ bias, const float* __restrict__ fc_b,
        float* __restrict__ w_all, float* __restrict__ c0) {
    __shared__ float red[256];
    int h = blockIdx.x;   // 0..3
    int f = threadIdx.x;  // 0..255
    float a0 = 0.f, a1 = 0.f, a2 = 0.f;
    for (int c = 0; c < HIDDEN; ++c) {
        float lw = lin_w[(size_t)(h * HIDDEN + c) * F_IN + f];
        a0 += att_src[h * HIDDEN + c] * lw;
        a1 += att_dst[h * HIDDEN + c] * lw;
        a2 += fc_w[h * HIDDEN + c] * lw;
    }
    w_all[(0 + h) * F_IN + f] = a0;
    w_all[(4 + h) * F_IN + f] = a1;
    w_all[(8 + h) * F_IN + f] = a2;
    if (h == 0) {
        red[f] = bias[f] * fc_w[f];
        __syncthreads();
        for (int s = 128; s; s >>= 1) {
            if (f < s) red[f] += red[f + s];
            __syncthreads();
        }
        if (f == 0) c0[0] = red[0] + fc_b[0];
    }
}

// ---- K1: per-node 256x12 matvec ----
__global__ __launch_bounds__(256) void node_kernel(
        const float* __restrict__ x, const float* __restrict__ w_all,
        float* __restrict__ srcfeat, float* __restrict__ dstfeat) {
    int tid  = blockIdx.x * 256 + threadIdx.x;
    int wave = tid >> 6;
    int lane = threadIdx.x & 63;
    int sub  = lane >> 4;
    int l16  = lane & 15;
    int n = wave * 4 + sub;
    if (n >= N_NODES) return;
    const float4* xr = (const float4*)x + (size_t)n * 64;
    const float4* wr = (const float4*)w_all;
    float p[12];
#pragma unroll
    for (int r = 0; r < 12; ++r) p[r] = 0.f;
#pragma unroll
    for (int k = 0; k < 4; ++k) {
        float4 xv = xr[l16 + 16 * k];
#pragma unroll
        for (int r = 0; r < 12; ++r) {
            float4 wv = wr[r * 64 + l16 + 16 * k];
            p[r] += xv.x * wv.x + xv.y * wv.y + xv.z * wv.z + xv.w * wv.w;
        }
    }
#pragma unroll
    for (int r = 0; r < 12; ++r) {
        float v = p[r];
        v += __shfl_xor(v, 1);
        v += __shfl_xor(v, 2);
        v += __shfl_xor(v, 4);
        v += __shfl_xor(v, 8);
        p[r] = v;
    }
    if (l16 == 0) {
        float* sf = srcfeat + (size_t)n * 8;
        sf[0] = p[0];  sf[1] = p[1];  sf[2] = p[2];  sf[3] = p[3];
        sf[4] = p[8];  sf[5] = p[9];  sf[6] = p[10]; sf[7] = p[11];
        float* df = dstfeat + (size_t)n * 4;
        df[0] = p[4];  df[1] = p[5];  df[2] = p[6];  df[3] = p[7];
    }
}

// =================== LDS-privatized counting sort ===================

__global__ __launch_bounds__(256) void hist2_kernel(
        const int* __restrict__ ei, int* __restrict__ hist) {
    __shared__ int lcnt[W_BUCKETS];
    int t = threadIdx.x, b = blockIdx.x;
    for (int i = t; i < W_BUCKETS; i += 256) lcnt[i] = 0;
    __syncthreads();
    int base = b * CHUNK;
    int end = base + CHUNK; if (end > N_EDGES) end = N_EDGES;
    for (int e = base + t; e < end; e += 256)
        atomicAdd(&lcnt[ei[N_EDGES + e] >> 8], 1);
    __syncthreads();
    for (int i = t; i < W_BUCKETS; i += 256) hist[i * B_SC + b] = lcnt[i];
}

__global__ __launch_bounds__(256) void scan1_kernel(
        const int* __restrict__ hist, int* __restrict__ bsum) {
    __shared__ int red[256];
    int t = threadIdx.x, b = blockIdx.x;
    int i = b * 256 + t;
    red[t] = (i < M_OFF) ? hist[i] : 0;
    __syncthreads();
    for (int s = 128; s; s >>= 1) {
        if (t < s) red[t] += red[t + s];
        __syncthreads();
    }
    if (t == 0) bsum[b] = red[0];
}

__global__ __launch_bounds__(1024) void scan2_kernel(int* __restrict__ bsum) {
    __shared__ int sc[1024];
    int t = threadIdx.x;
    int v = (t < NB1) ? bsum[t] : 0;
    sc[t] = v;
    __syncthreads();
    for (int off = 1; off < 1024; off <<= 1) {
        int tmp = (t >= off) ? sc[t - off] : 0;
        __syncthreads();
        sc[t] += tmp;
        __syncthreads();
    }
    if (t < NB1) bsum[t] = sc[t] - v;  // exclusive
}

__global__ __launch_bounds__(256) void scan3_kernel(
        int* __restrict__ hist, const int* __restrict__ bsum) {
    __shared__ int sc[256];
    int t = threadIdx.x, b = blockIdx.x;
    int i = b * 256 + t;
    int v = (i < M_OFF) ? hist[i] : 0;
    sc[t] = v;
    __syncthreads();
    for (int off = 1; off < 256; off <<= 1) {
        int tmp = (t >= off) ? sc[t - off] : 0;
        __syncthreads();
        sc[t] += tmp;
        __syncthreads();
    }
    if (i < M_OFF) hist[i] = bsum[b] + sc[t] - v;
}

__global__ __launch_bounds__(256) void scatter2_kernel(
        const int* __restrict__ ei, const int* __restrict__ goff,
        int* __restrict__ sorted) {
    __shared__ int lbase[W_BUCKETS];
    int t = threadIdx.x, b = blockIdx.x;
    for (int i = t; i < W_BUCKETS; i += 256) lbase[i] = goff[i * B_SC + b];
    __syncthreads();
    int base = b * CHUNK;
    int end = base + CHUNK; if (end > N_EDGES) end = N_EDGES;
    for (int e = base + t; e < end; e += 256) {
        int s = ei[e];
        int d = ei[N_EDGES + e];
        int pos = atomicAdd(&lbase[d >> 8], 1);
        sorted[pos] = s | ((d & 255) << 17);
    }
}

// ---- split agg: SPLIT sub-blocks per bucket, each writes an 8x256 partial ----
__global__ __launch_bounds__(256) void agg3_kernel(
        const int* __restrict__ sorted, const int* __restrict__ goff,
        const float* __restrict__ srcfeat, const float* __restrict__ dstfeat,
        float* __restrict__ part, int split) {
    __shared__ float acc[8][256];
    __shared__ float4 lad[256];
    int t = threadIdx.x;
    int k = blockIdx.x / split;   // bucket
    int s = blockIdx.x % split;   // sub-range
#pragma unroll
    for (int i = 0; i < 8; ++i) acc[i][t] = 0.f;
    int n0 = k * 256 + t;
    lad[t] = (n0 < N_NODES) ? *(const float4*)(dstfeat + (size_t)n0 * 4)
                            : make_float4(0.f, 0.f, 0.f, 0.f);
    __syncthreads();
    int bk_begin = goff[k * B_SC];
    int bk_end = (k == W_BUCKETS - 1) ? N_EDGES : goff[(k + 1) * B_SC];
    int len = bk_end - bk_begin;
    int begin = bk_begin + (int)(((long long)len * s) / split);
    int end   = bk_begin + (int)(((long long)len * (s + 1)) / split);
    for (int i = begin + t; i < end; i += 256) {
        int p = sorted[i];
        int si = p & 0x1FFFF;
        int off = p >> 17;
        const float4* sp = (const float4*)(srcfeat + (size_t)si * 8);
        float4 as = sp[0];
        float4 g  = sp[1];
        float4 ad = lad[off];
        float s0 = as.x + ad.x, s1 = as.y + ad.y, s2 = as.z + ad.z, s3 = as.w + ad.w;
        float e0 = __expf(s0 > 0.f ? s0 : NEG_SLOPE * s0);
        float e1 = __expf(s1 > 0.f ? s1 : NEG_SLOPE * s1);
        float e2 = __expf(s2 > 0.f ? s2 : NEG_SLOPE * s2);
        float e3 = __expf(s3 > 0.f ? s3 : NEG_SLOPE * s3);
        atomicAdd(&acc[0][off], e0);
        atomicAdd(&acc[1][off], e1);
        atomicAdd(&acc[2][off], e2);
        atomicAdd(&acc[3][off], e3);
        atomicAdd(&acc[4][off], e0 * g.x);
        atomicAdd(&acc[5][off], e1 * g.y);
        atomicAdd(&acc[6][off], e2 * g.z);
        atomicAdd(&acc[7][off], e3 * g.w);
    }
    __syncthreads();
    float* pb = part + (size_t)blockIdx.x * 2048;
#pragma unroll
    for (int h = 0; h < 8; ++h) pb[h * 256 + t] = acc[h][t];
}

__global__ __launch_bounds__(256) void merge_kernel(
        const float* __restrict__ part, const float* __restrict__ c0,
        float* __restrict__ out, int split) {
    int t = threadIdx.x, k = blockIdx.x;
    int n = k * 256 + t;
    if (n >= N_NODES) return;
    float de[4] = {0.f, 0.f, 0.f, 0.f};
    float nu[4] = {0.f, 0.f, 0.f, 0.f};
    for (int s = 0; s < split; ++s) {
        const float* pb = part + (size_t)(k * split + s) * 2048;
#pragma unroll
        for (int h = 0; h < 4; ++h) {
            de[h] += pb[h * 256 + t];
            nu[h] += pb[(h + 4) * 256 + t];
        }
    }
    float y = c0[0];
#pragma unroll
    for (int h = 0; h < 4; ++h) y += nu[h] / (de[h] + 1e-16f);
    out[n] = y;
}

// ---- single-block-per-bucket agg (used when ws can't hold partials) ----
__global__ __launch_bounds__(256) void agg2_kernel(
        const int* __restrict__ sorted, const int* __restrict__ goff,
        const float* __restrict__ srcfeat, const float* __restrict__ dstfeat,
        const float* __restrict__ c0, float* __restrict__ out) {
    __shared__ float acc[8][256];
    __shared__ float4 lad[256];
    int t = threadIdx.x, k = blockIdx.x;
#pragma unroll
    for (int i = 0; i < 8; ++i) acc[i][t] = 0.f;
    int n0 = k * 256 + t;
    lad[t] = (n0 < N_NODES) ? *(const float4*)(dstfeat + (size_t)n0 * 4)
                            : make_float4(0.f, 0.f, 0.f, 0.f);
    __syncthreads();
    int begin = goff[k * B_SC];
    int end = (k == W_BUCKETS - 1) ? N_EDGES : goff[(k + 1) * B_SC];
    for (int i = begin + t; i < end; i += 256) {
        int p = sorted[i];
        int si = p & 0x1FFFF;
        int off = p >> 17;
        const float4* sp = (const float4*)(srcfeat + (size_t)si * 8);
        float4 as = sp[0];
        float4 g  = sp[1];
        float4 ad = lad[off];
        float s0 = as.x + ad.x, s1 = as.y + ad.y, s2 = as.z + ad.z, s3 = as.w + ad.w;
        float e0 = __expf(s0 > 0.f ? s0 : NEG_SLOPE * s0);
        float e1 = __expf(s1 > 0.f ? s1 : NEG_SLOPE * s1);
        float e2 = __expf(s2 > 0.f ? s2 : NEG_SLOPE * s2);
        float e3 = __expf(s3 > 0.f ? s3 : NEG_SLOPE * s3);
        atomicAdd(&acc[0][off], e0);
        atomicAdd(&acc[1][off], e1);
        atomicAdd(&acc[2][off], e2);
        atomicAdd(&acc[3][off], e3);
        atomicAdd(&acc[4][off], e0 * g.x);
        atomicAdd(&acc[5][off], e1 * g.y);
        atomicAdd(&acc[6][off], e2 * g.z);
        atomicAdd(&acc[7][off], e3 * g.w);
    }
    __syncthreads();
    if (n0 < N_NODES) {
        float y = c0[0];
        y += acc[4][t] / (acc[0][t] + 1e-16f);
        y += acc[5][t] / (acc[1][t] + 1e-16f);
        y += acc[6][t] / (acc[2][t] + 1e-16f);
        y += acc[7][t] / (acc[3][t] + 1e-16f);
        out[n0] = y;
    }
}

// =================== fallback atomic path (tiny ws) ===================

__global__ __launch_bounds__(256) void init_nd_kernel(
        float* __restrict__ num, float* __restrict__ den) {
    int i = blockIdx.x * 256 + threadIdx.x;
    if (i < N_NODES * 4) { num[i] = 0.f; den[i] = 0.f; }
}

__global__ __launch_bounds__(256) void edge_acc2_kernel(
        const int* __restrict__ ei, const float* __restrict__ srcfeat,
        const float* __restrict__ dstfeat, float* __restrict__ num,
        float* __restrict__ den) {
    int e = blockIdx.x * 256 + threadIdx.x;
    if (e >= N_EDGES) return;
    int s = ei[e];
    int d = ei[N_EDGES + e];
    const float4* sp = (const float4*)(srcfeat + (size_t)s * 8);
    float4 as = sp[0];
    float4 g  = sp[1];
    float4 ad = *(const float4*)(dstfeat + (size_t)d * 4);
    float sc[4] = {as.x + ad.x, as.y + ad.y, as.z + ad.z, as.w + ad.w};
    float gg[4] = {g.x, g.y, g.z, g.w};
    float* np = num + (size_t)d * 4;
    float* dp = den + (size_t)d * 4;
#pragma unroll
    for (int h = 0; h < 4; ++h) {
        float v = sc[h] > 0.f ? sc[h] : NEG_SLOPE * sc[h];
        float ex = __expf(v);
        atomicAdd(dp + h, ex);
        atomicAdd(np + h, ex * gg[h]);
    }
}

__global__ __launch_bounds__(256) void finalize_kernel(
        const float* __restrict__ num, const float* __restrict__ den,
        const float* __restrict__ c0, float* __restrict__ out) {
    int n = blockIdx.x * 256 + threadIdx.x;
    if (n >= N_NODES) return;
    float4 nu = *(const float4*)(num + (size_t)n * 4);
    float4 de = *(const float4*)(den + (size_t)n * 4);
    out[n] = c0[0]
           + nu.x / (de.x + 1e-16f)
           + nu.y / (de.y + 1e-16f)
           + nu.z / (de.z + 1e-16f)
           + nu.w / (de.w + 1e-16f);
}

extern "C" void kernel_launch(void* const* d_in, const int* in_sizes, int n_in,
                              void* d_out, int out_size, void* d_ws, size_t ws_size,
                              hipStream_t stream) {
    const float* x       = (const float*)d_in[0];
    const int*   ei      = (const int*)d_in[1];
    const float* lin_w   = (const float*)d_in[2];
    const float* att_src = (const float*)d_in[3];
    const float* att_dst = (const float*)d_in[4];
    const float* bias    = (const float*)d_in[5];
    const float* fc_w    = (const float*)d_in[6];
    const float* fc_b    = (const float*)d_in[7];
    float* out = (float*)d_out;

    float* ws = (float*)d_ws;
    float* w_all   = ws;            // 3072 (+pad to 4096)
    float* c0      = ws + 3072;
    float* srcfeat = ws + 4096;     // 800000
    float* dstfeat = ws + 804096;   // 400000

    prep_kernel<<<4, 256, 0, stream>>>(lin_w, att_src, att_dst, fc_w, bias, fc_b, w_all, c0);
    node_kernel<<<(N_NODES + 15) / 16, 256, 0, stream>>>(x, w_all, srcfeat, dstfeat);

    const size_t base_words = 2955264;  // up to end of sorted
    if (ws_size >= base_words * 4) {
        int* hist   = (int*)(ws + 1204096);  // 150144 (becomes offsets)
        int* bsum   = (int*)(ws + 1354240);  // 1024
        int* sorted = (int*)(ws + 1355264);  // 1600000
        float* part = ws + base_words;       // split * 391 * 2048 floats

        hist2_kernel<<<B_SC, 256, 0, stream>>>(ei, hist);
        scan1_kernel<<<NB1, 256, 0, stream>>>(hist, bsum);
        scan2_kernel<<<1, 1024, 0, stream>>>(bsum);
        scan3_kernel<<<NB1, 256, 0, stream>>>(hist, bsum);
        scatter2_kernel<<<B_SC, 256, 0, stream>>>(ei, hist, sorted);

        size_t per_split_words = (size_t)W_BUCKETS * 2048;
        int split = (int)((ws_size / 4 - base_words) / per_split_words);
        if (split > MAX_SPLIT) split = MAX_SPLIT;
        if (split >= 2) {
            agg3_kernel<<<W_BUCKETS * split, 256, 0, stream>>>(
                sorted, hist, srcfeat, dstfeat, part, split);
            merge_kernel<<<W_BUCKETS, 256, 0, stream>>>(part, c0, out, split);
        } else {
            agg2_kernel<<<W_BUCKETS, 256, 0, stream>>>(
                sorted, hist, srcfeat, dstfeat, c0, out);
        }
    } else {
        float* num = ws + 1204096;
        float* den = ws + 1604096;
        init_nd_kernel<<<(N_NODES * 4 + 255) / 256, 256, 0, stream>>>(num, den);
        edge_acc2_kernel<<<N_EDGES / 256, 256, 0, stream>>>(ei, srcfeat, dstfeat, num, den);
        finalize_kernel<<<(N_NODES + 255) / 256, 256, 0, stream>>>(num, den, c0, out);
    }
}

// Round 5
// 274.236 us; speedup vs baseline: 3.9881x; 1.1973x over previous
//
#include <hip/hip_runtime.h>
#include <math.h>

#define N_NODES 100000
#define N_EDGES 1600000
#define F_IN 256
#define HIDDEN 64
#define NEG_SLOPE 0.2f

#define BSHIFT 7               // bucket = dst>>7 (128 nodes/bucket)
#define BMASK 127
#define W_BUCKETS 782          // ceil(100000/128)
#define B_SC 512               // hist/scatter blocks
#define CHUNK 3125             // 512*3125 = 1600000 exactly
#define M_OFF (W_BUCKETS * B_SC)  // 400384
#define NB1 1564               // ceil(M_OFF/256)
#define CAP 2560               // LDS edge capacity per bucket (mean 2048, +8 sigma)

// ---- K0: fold att_src/att_dst/fc_w through lin_w ----
__global__ __launch_bounds__(256) void prep_kernel(
        const float* __restrict__ lin_w, const float* __restrict__ att_src,
        const float* __restrict__ att_dst, const float* __restrict__ fc_w,
        const float* __restrict__ bias, const float* __restrict__ fc_b,
        float* __restrict__ w_all, float* __restrict__ c0) {
    __shared__ float red[256];
    int h = blockIdx.x;   // 0..3
    int f = threadIdx.x;  // 0..255
    float a0 = 0.f, a1 = 0.f, a2 = 0.f;
    for (int c = 0; c < HIDDEN; ++c) {
        float lw = lin_w[(size_t)(h * HIDDEN + c) * F_IN + f];
        a0 += att_src[h * HIDDEN + c] * lw;
        a1 += att_dst[h * HIDDEN + c] * lw;
        a2 += fc_w[h * HIDDEN + c] * lw;
    }
    w_all[(0 + h) * F_IN + f] = a0;
    w_all[(4 + h) * F_IN + f] = a1;
    w_all[(8 + h) * F_IN + f] = a2;
    if (h == 0) {
        red[f] = bias[f] * fc_w[f];
        __syncthreads();
        for (int s = 128; s; s >>= 1) {
            if (f < s) red[f] += red[f + s];
            __syncthreads();
        }
        if (f == 0) c0[0] = red[0] + fc_b[0];
    }
}

// ---- K1: per-node 256x12 matvec ----
__global__ __launch_bounds__(256) void node_kernel(
        const float* __restrict__ x, const float* __restrict__ w_all,
        float* __restrict__ srcfeat, float* __restrict__ dstfeat) {
    int tid  = blockIdx.x * 256 + threadIdx.x;
    int wave = tid >> 6;
    int lane = threadIdx.x & 63;
    int sub  = lane >> 4;
    int l16  = lane & 15;
    int n = wave * 4 + sub;
    if (n >= N_NODES) return;
    const float4* xr = (const float4*)x + (size_t)n * 64;
    const float4* wr = (const float4*)w_all;
    float p[12];
#pragma unroll
    for (int r = 0; r < 12; ++r) p[r] = 0.f;
#pragma unroll
    for (int k = 0; k < 4; ++k) {
        float4 xv = xr[l16 + 16 * k];
#pragma unroll
        for (int r = 0; r < 12; ++r) {
            float4 wv = wr[r * 64 + l16 + 16 * k];
            p[r] += xv.x * wv.x + xv.y * wv.y + xv.z * wv.z + xv.w * wv.w;
        }
    }
#pragma unroll
    for (int r = 0; r < 12; ++r) {
        float v = p[r];
        v += __shfl_xor(v, 1);
        v += __shfl_xor(v, 2);
        v += __shfl_xor(v, 4);
        v += __shfl_xor(v, 8);
        p[r] = v;
    }
    if (l16 == 0) {
        float* sf = srcfeat + (size_t)n * 8;
        sf[0] = p[0];  sf[1] = p[1];  sf[2] = p[2];  sf[3] = p[3];
        sf[4] = p[8];  sf[5] = p[9];  sf[6] = p[10]; sf[7] = p[11];
        float* df = dstfeat + (size_t)n * 4;
        df[0] = p[4];  df[1] = p[5];  df[2] = p[6];  df[3] = p[7];
    }
}

// =================== LDS-privatized counting sort (bucket = 128 nodes) ===================

__global__ __launch_bounds__(256) void hist2_kernel(
        const int* __restrict__ ei, int* __restrict__ hist) {
    __shared__ int lcnt[W_BUCKETS];
    int t = threadIdx.x, b = blockIdx.x;
    for (int i = t; i < W_BUCKETS; i += 256) lcnt[i] = 0;
    __syncthreads();
    int base = b * CHUNK;
    int end = base + CHUNK; if (end > N_EDGES) end = N_EDGES;
    for (int e = base + t; e < end; e += 256)
        atomicAdd(&lcnt[ei[N_EDGES + e] >> BSHIFT], 1);
    __syncthreads();
    for (int i = t; i < W_BUCKETS; i += 256) hist[i * B_SC + b] = lcnt[i];
}

__global__ __launch_bounds__(256) void scan1_kernel(
        const int* __restrict__ hist, int* __restrict__ bsum) {
    __shared__ int red[256];
    int t = threadIdx.x, b = blockIdx.x;
    int i = b * 256 + t;
    red[t] = (i < M_OFF) ? hist[i] : 0;
    __syncthreads();
    for (int s = 128; s; s >>= 1) {
        if (t < s) red[t] += red[t + s];
        __syncthreads();
    }
    if (t == 0) bsum[b] = red[0];
}

// exclusive scan of NB1 block sums; 1024 threads x 2 serial
__global__ __launch_bounds__(1024) void scan2_kernel(int* __restrict__ bsum) {
    __shared__ int sc[1024];
    int t = threadIdx.x;
    int i0 = t * 2, i1 = t * 2 + 1;
    int v0 = (i0 < NB1) ? bsum[i0] : 0;
    int v1 = (i1 < NB1) ? bsum[i1] : 0;
    int s = v0 + v1;
    sc[t] = s;
    __syncthreads();
    for (int off = 1; off < 1024; off <<= 1) {
        int tmp = (t >= off) ? sc[t - off] : 0;
        __syncthreads();
        sc[t] += tmp;
        __syncthreads();
    }
    int base = sc[t] - s;  // exclusive
    if (i0 < NB1) bsum[i0] = base;
    if (i1 < NB1) bsum[i1] = base + v0;
}

__global__ __launch_bounds__(256) void scan3_kernel(
        int* __restrict__ hist, const int* __restrict__ bsum) {
    __shared__ int sc[256];
    int t = threadIdx.x, b = blockIdx.x;
    int i = b * 256 + t;
    int v = (i < M_OFF) ? hist[i] : 0;
    sc[t] = v;
    __syncthreads();
    for (int off = 1; off < 256; off <<= 1) {
        int tmp = (t >= off) ? sc[t - off] : 0;
        __syncthreads();
        sc[t] += tmp;
        __syncthreads();
    }
    if (i < M_OFF) hist[i] = bsum[b] + sc[t] - v;
}

// place edges: sorted[pos] = src | (dst&127)<<17
__global__ __launch_bounds__(256) void scatter2_kernel(
        const int* __restrict__ ei, const int* __restrict__ goff,
        int* __restrict__ sorted) {
    __shared__ int lbase[W_BUCKETS];
    int t = threadIdx.x, b = blockIdx.x;
    for (int i = t; i < W_BUCKETS; i += 256) lbase[i] = goff[i * B_SC + b];
    __syncthreads();
    int base = b * CHUNK;
    int end = base + CHUNK; if (end > N_EDGES) end = N_EDGES;
    for (int e = base + t; e < end; e += 256) {
        int s = ei[e];
        int d = ei[N_EDGES + e];
        int pos = atomicAdd(&lbase[d >> BSHIFT], 1);
        sorted[pos] = s | ((d & BMASK) << 17);
    }
}

// ---- agg4: per-bucket in-LDS fine sort + atomic-free per-node aggregation ----
__global__ __launch_bounds__(256) void agg4_kernel(
        const int* __restrict__ sorted, const int* __restrict__ goff,
        const float* __restrict__ srcfeat, const float* __restrict__ dstfeat,
        const float* __restrict__ c0, float* __restrict__ out) {
    __shared__ int eds[CAP];
    __shared__ int srt[CAP];
    __shared__ int cnt[128];   // hist, then cursor
    __shared__ int bnd[129];   // exclusive bounds
    int t = threadIdx.x, k = blockIdx.x;
    int begin = goff[k * B_SC];
    int end = (k == W_BUCKETS - 1) ? N_EDGES : goff[(k + 1) * B_SC];
    int len = end - begin;
    int lcap = len < CAP ? len : CAP;
    if (t < 128) cnt[t] = 0;
    __syncthreads();
    // load + histogram (1 LDS atomic/edge)
    for (int i = t; i < lcap; i += 256) {
        int p = sorted[begin + i];
        eds[i] = p;
        atomicAdd(&cnt[p >> 17], 1);
    }
    __syncthreads();
    // exclusive scan of 128 bins -> bnd[0..128]
    if (t < 128) bnd[t + 1] = cnt[t];
    __syncthreads();
    for (int off = 1; off < 128; off <<= 1) {
        int v = 0;
        if (t < 128 && t >= off) v = bnd[t + 1 - off];
        __syncthreads();
        if (t < 128) bnd[t + 1] += v;
        __syncthreads();
    }
    if (t == 0) bnd[0] = 0;
    if (t < 128) cnt[t] = (t == 0) ? 0 : bnd[t];  // cursor = exclusive start
    __syncthreads();
    // in-LDS scatter to per-node runs (1 returning LDS atomic/edge)
    for (int i = t; i < lcap; i += 256) {
        int p = eds[i];
        int pos = atomicAdd(&cnt[p >> 17], 1);
        srt[pos] = p & 0x1FFFF;
    }
    __syncthreads();
    // per-node aggregation, atomic-free, fused finalize
    if (t < 128) {
        int n0 = k * 128 + t;
        if (n0 < N_NODES) {
            float4 ad = *(const float4*)(dstfeat + (size_t)n0 * 4);
            float de0 = 0.f, de1 = 0.f, de2 = 0.f, de3 = 0.f;
            float nu0 = 0.f, nu1 = 0.f, nu2 = 0.f, nu3 = 0.f;
            int b0 = bnd[t], e0 = bnd[t + 1];
            for (int i = b0; i < e0; ++i) {
                int s = srt[i];
                const float4* sp = (const float4*)(srcfeat + (size_t)s * 8);
                float4 as = sp[0];
                float4 g  = sp[1];
                float s0 = as.x + ad.x, s1 = as.y + ad.y;
                float s2 = as.z + ad.z, s3 = as.w + ad.w;
                float x0 = __expf(s0 > 0.f ? s0 : NEG_SLOPE * s0);
                float x1 = __expf(s1 > 0.f ? s1 : NEG_SLOPE * s1);
                float x2 = __expf(s2 > 0.f ? s2 : NEG_SLOPE * s2);
                float x3 = __expf(s3 > 0.f ? s3 : NEG_SLOPE * s3);
                de0 += x0; de1 += x1; de2 += x2; de3 += x3;
                nu0 += x0 * g.x; nu1 += x1 * g.y; nu2 += x2 * g.z; nu3 += x3 * g.w;
            }
            // overflow edges (len > CAP): scan directly from global (rare/never)
            for (int i = CAP; i < len; ++i) {
                int p = sorted[begin + i];
                if ((p >> 17) == t) {
                    int s = p & 0x1FFFF;
                    const float4* sp = (const float4*)(srcfeat + (size_t)s * 8);
                    float4 as = sp[0];
                    float4 g  = sp[1];
                    float s0 = as.x + ad.x, s1 = as.y + ad.y;
                    float s2 = as.z + ad.z, s3 = as.w + ad.w;
                    float x0 = __expf(s0 > 0.f ? s0 : NEG_SLOPE * s0);
                    float x1 = __expf(s1 > 0.f ? s1 : NEG_SLOPE * s1);
                    float x2 = __expf(s2 > 0.f ? s2 : NEG_SLOPE * s2);
                    float x3 = __expf(s3 > 0.f ? s3 : NEG_SLOPE * s3);
                    de0 += x0; de1 += x1; de2 += x2; de3 += x3;
                    nu0 += x0 * g.x; nu1 += x1 * g.y; nu2 += x2 * g.z; nu3 += x3 * g.w;
                }
            }
            float y = c0[0]
                    + nu0 / (de0 + 1e-16f)
                    + nu1 / (de1 + 1e-16f)
                    + nu2 / (de2 + 1e-16f)
                    + nu3 / (de3 + 1e-16f);
            out[n0] = y;
        }
    }
}

// =================== fallback atomic path (tiny ws) ===================

__global__ __launch_bounds__(256) void init_nd_kernel(
        float* __restrict__ num, float* __restrict__ den) {
    int i = blockIdx.x * 256 + threadIdx.x;
    if (i < N_NODES * 4) { num[i] = 0.f; den[i] = 0.f; }
}

__global__ __launch_bounds__(256) void edge_acc2_kernel(
        const int* __restrict__ ei, const float* __restrict__ srcfeat,
        const float* __restrict__ dstfeat, float* __restrict__ num,
        float* __restrict__ den) {
    int e = blockIdx.x * 256 + threadIdx.x;
    if (e >= N_EDGES) return;
    int s = ei[e];
    int d = ei[N_EDGES + e];
    const float4* sp = (const float4*)(srcfeat + (size_t)s * 8);
    float4 as = sp[0];
    float4 g  = sp[1];
    float4 ad = *(const float4*)(dstfeat + (size_t)d * 4);
    float sc[4] = {as.x + ad.x, as.y + ad.y, as.z + ad.z, as.w + ad.w};
    float gg[4] = {g.x, g.y, g.z, g.w};
    float* np = num + (size_t)d * 4;
    float* dp = den + (size_t)d * 4;
#pragma unroll
    for (int h = 0; h < 4; ++h) {
        float v = sc[h] > 0.f ? sc[h] : NEG_SLOPE * sc[h];
        float ex = __expf(v);
        atomicAdd(dp + h, ex);
        atomicAdd(np + h, ex * gg[h]);
    }
}

__global__ __launch_bounds__(256) void finalize_kernel(
        const float* __restrict__ num, const float* __restrict__ den,
        const float* __restrict__ c0, float* __restrict__ out) {
    int n = blockIdx.x * 256 + threadIdx.x;
    if (n >= N_NODES) return;
    float4 nu = *(const float4*)(num + (size_t)n * 4);
    float4 de = *(const float4*)(den + (size_t)n * 4);
    out[n] = c0[0]
           + nu.x / (de.x + 1e-16f)
           + nu.y / (de.y + 1e-16f)
           + nu.z / (de.z + 1e-16f)
           + nu.w / (de.w + 1e-16f);
}

extern "C" void kernel_launch(void* const* d_in, const int* in_sizes, int n_in,
                              void* d_out, int out_size, void* d_ws, size_t ws_size,
                              hipStream_t stream) {
    const float* x       = (const float*)d_in[0];
    const int*   ei      = (const int*)d_in[1];
    const float* lin_w   = (const float*)d_in[2];
    const float* att_src = (const float*)d_in[3];
    const float* att_dst = (const float*)d_in[4];
    const float* bias    = (const float*)d_in[5];
    const float* fc_w    = (const float*)d_in[6];
    const float* fc_b    = (const float*)d_in[7];
    float* out = (float*)d_out;

    float* ws = (float*)d_ws;
    float* w_all   = ws;            // 3072 (+pad to 4096)
    float* c0      = ws + 3072;
    float* srcfeat = ws + 4096;     // 800000
    float* dstfeat = ws + 804096;   // 400000

    prep_kernel<<<4, 256, 0, stream>>>(lin_w, att_src, att_dst, fc_w, bias, fc_b, w_all, c0);
    node_kernel<<<(N_NODES + 15) / 16, 256, 0, stream>>>(x, w_all, srcfeat, dstfeat);

    // layout: hist @1204096 (400384) | bsum @1604480 (1564, pad) | sorted @1606144 (1600000)
    const size_t need_words = 3206144;
    if (ws_size >= need_words * 4) {
        int* hist   = (int*)(ws + 1204096);
        int* bsum   = (int*)(ws + 1604480);
        int* sorted = (int*)(ws + 1606144);

        hist2_kernel<<<B_SC, 256, 0, stream>>>(ei, hist);
        scan1_kernel<<<NB1, 256, 0, stream>>>(hist, bsum);
        scan2_kernel<<<1, 1024, 0, stream>>>(bsum);
        scan3_kernel<<<NB1, 256, 0, stream>>>(hist, bsum);
        scatter2_kernel<<<B_SC, 256, 0, stream>>>(ei, hist, sorted);
        agg4_kernel<<<W_BUCKETS, 256, 0, stream>>>(sorted, hist, srcfeat, dstfeat, c0, out);
    } else {
        float* num = ws + 1204096;
        float* den = ws + 1604096;
        init_nd_kernel<<<(N_NODES * 4 + 255) / 256, 256, 0, stream>>>(num, den);
        edge_acc2_kernel<<<N_EDGES / 256, 256, 0, stream>>>(ei, srcfeat, dstfeat, num, den);
        finalize_kernel<<<(N_NODES + 255) / 256, 256, 0, stream>>>(num, den, c0, out);
    }
}